// Round 1
// baseline (214.396 us; speedup 1.0000x reference)
//
#include <hip/hip_runtime.h>
#include <math.h>

#define THREADS 256
#define IMG 4

// LDS float offsets (total 11880 floats = 47.5 KB -> 3 blocks/CU by LDS)
#define S_X    0        // 4*1152 (row stride 36, image stride 1152)
#define S_P2   0        // alias after conv1: 4*404 = 1616
#define S_FC1  1616     // 480
#define S_FC2  2096     // 336
#define S_LOG  2432     // 40
#define S_P1   4608     // 4*1180 (image stride 1180, row stride 14)
#define S_W1   9328     // 150 (+2 pad)
#define S_W2   9480     // 2400
#define LDS_TOT 11880

__global__ __launch_bounds__(THREADS) void lenet_kernel(
    const float* __restrict__ x,
    const float* __restrict__ w1,
    const float* __restrict__ w2,
    const float* __restrict__ fw1,
    const float* __restrict__ fw2,
    const float* __restrict__ fc3w,
    const float* __restrict__ fc3b,
    float* __restrict__ out)
{
    __shared__ __align__(16) float lds[LDS_TOT];
    const int tid = threadIdx.x;
    const int blk = blockIdx.x;

    // ---- stage x (IMG images) into LDS, row stride 36 ----
    {
        const float4* src = (const float4*)(x + (size_t)blk * (IMG * 1024));
        for (int e = tid; e < IMG * 256; e += THREADS) {
            int m = e >> 8;
            int rem = e & 255;
            int y = rem >> 3;
            int k = rem & 7;
            *(float4*)(lds + S_X + m * 1152 + y * 36 + k * 4) = src[e];
        }
    }
    // ---- stage conv weights ----
    for (int e = tid; e < 150; e += THREADS) lds[S_W1 + e] = w1[e];
    {
        const float4* src = (const float4*)w2;
        for (int e = tid; e < 600; e += THREADS)
            *(float4*)(lds + S_W2 + e * 4) = src[e];
    }
    __syncthreads();

    // ---- conv1 (1->6, 5x5, 28x28) + relu + 2x2 pool -> p1 [m][6][14][14] ----
    // task = (m, c, pooled-row i, half): 7 pooled outputs each; 672 tasks
    for (int task = tid; task < IMG * 168; task += THREADS) {
        int m = task / 168;
        int r = task % 168;
        int c = r % 6;          // c innermost: input addr independent of c -> broadcast
        int q = r / 6;          // 0..27
        int i = q >> 1;         // pooled row 0..13
        int half = q & 1;       // pooled cols 7*half .. 7*half+6
        const float* xim = lds + S_X + m * 1152 + half * 14;
        const float* wc  = lds + S_W1 + c * 25;
        float acc0[14], acc1[14];
        #pragma unroll
        for (int j = 0; j < 14; ++j) { acc0[j] = 0.f; acc1[j] = 0.f; }
        #pragma unroll
        for (int t = 0; t < 6; ++t) {
            float row[18];
            const float* rp = xim + (2 * i + t) * 36;
            #pragma unroll
            for (int qq = 0; qq < 9; ++qq) {
                float2 v = *(const float2*)(rp + 2 * qq);
                row[2 * qq] = v.x; row[2 * qq + 1] = v.y;
            }
            if (t < 5) {
                #pragma unroll
                for (int kx = 0; kx < 5; ++kx) {
                    float w = wc[t * 5 + kx];
                    #pragma unroll
                    for (int xx = 0; xx < 14; ++xx)
                        acc0[xx] = fmaf(row[xx + kx], w, acc0[xx]);
                }
            }
            if (t >= 1) {
                #pragma unroll
                for (int kx = 0; kx < 5; ++kx) {
                    float w = wc[(t - 1) * 5 + kx];
                    #pragma unroll
                    for (int xx = 0; xx < 14; ++xx)
                        acc1[xx] = fmaf(row[xx + kx], w, acc1[xx]);
                }
            }
        }
        // pool 2x2 of the two conv rows; relu == clamp at 0 (max of relu = relu of max)
        float* dst = lds + S_P1 + m * 1180 + c * 196 + i * 14 + half * 7;
        #pragma unroll
        for (int j = 0; j < 7; ++j) {
            float v = fmaxf(fmaxf(acc0[2 * j], acc0[2 * j + 1]),
                            fmaxf(acc1[2 * j], acc1[2 * j + 1]));
            dst[j] = fmaxf(v, 0.f);
        }
    }
    __syncthreads();

    // ---- conv2 (6->16, 5x5, 10x10) + relu + pool -> p2 [m][16][5][5] ----
    // task = (m, i, oc): oc innermost -> input reads are same-address broadcasts
    for (int task = tid; task < IMG * 80; task += THREADS) {
        int m = task / 80;
        int r = task % 80;
        int oc = r % 16;
        int i  = r / 16;        // pooled row 0..4
        const float* pim = lds + S_P1 + m * 1180;
        const float* wb  = lds + S_W2 + oc * 150;
        float acc0[10], acc1[10];
        #pragma unroll
        for (int j = 0; j < 10; ++j) { acc0[j] = 0.f; acc1[j] = 0.f; }
        for (int ic = 0; ic < 6; ++ic) {
            const float* pc = pim + ic * 196;
            const float* wc = wb + ic * 25;
            #pragma unroll
            for (int t = 0; t < 6; ++t) {
                float row[14];
                const float* rp = pc + (2 * i + t) * 14;
                #pragma unroll
                for (int qq = 0; qq < 7; ++qq) {
                    float2 v = *(const float2*)(rp + 2 * qq);
                    row[2 * qq] = v.x; row[2 * qq + 1] = v.y;
                }
                if (t < 5) {
                    #pragma unroll
                    for (int kx = 0; kx < 5; ++kx) {
                        float w = wc[t * 5 + kx];
                        #pragma unroll
                        for (int xx = 0; xx < 10; ++xx)
                            acc0[xx] = fmaf(row[xx + kx], w, acc0[xx]);
                    }
                }
                if (t >= 1) {
                    #pragma unroll
                    for (int kx = 0; kx < 5; ++kx) {
                        float w = wc[(t - 1) * 5 + kx];
                        #pragma unroll
                        for (int xx = 0; xx < 10; ++xx)
                            acc1[xx] = fmaf(row[xx + kx], w, acc1[xx]);
                    }
                }
            }
        }
        // p2 layout matches torch channel-major flatten: k = oc*25 + i*5 + j
        float* dst = lds + S_P2 + m * 404 + oc * 25 + i * 5;
        #pragma unroll
        for (int j = 0; j < 5; ++j) {
            float v = fmaxf(fmaxf(acc0[2 * j], acc0[2 * j + 1]),
                            fmaxf(acc1[2 * j], acc1[2 * j + 1]));
            dst[j] = fmaxf(v, 0.f);
        }
    }
    __syncthreads();

    // ---- fc1: [400] -> [120], relu. m innermost: 4 lanes share each weight row ----
    for (int task = tid; task < IMG * 120; task += THREADS) {
        int m = task & 3;
        int n = task >> 2;
        const float4* a = (const float4*)(lds + S_P2 + m * 404);
        const float4* w = (const float4*)(fw1 + n * 400);
        float acc = 0.f;
        #pragma unroll 5
        for (int k = 0; k < 100; ++k) {
            float4 av = a[k], wv = w[k];
            acc = fmaf(av.x, wv.x, acc);
            acc = fmaf(av.y, wv.y, acc);
            acc = fmaf(av.z, wv.z, acc);
            acc = fmaf(av.w, wv.w, acc);
        }
        lds[S_FC1 + m * 120 + n] = fmaxf(acc, 0.f);
    }
    __syncthreads();

    // ---- fc2: [120] -> [84], relu ----
    for (int task = tid; task < IMG * 84; task += THREADS) {
        int m = task & 3;
        int n = task >> 2;
        const float4* a = (const float4*)(lds + S_FC1 + m * 120);
        const float4* w = (const float4*)(fw2 + n * 120);
        float acc = 0.f;
        #pragma unroll
        for (int k = 0; k < 30; ++k) {
            float4 av = a[k], wv = w[k];
            acc = fmaf(av.x, wv.x, acc);
            acc = fmaf(av.y, wv.y, acc);
            acc = fmaf(av.z, wv.z, acc);
            acc = fmaf(av.w, wv.w, acc);
        }
        lds[S_FC2 + m * 84 + n] = fmaxf(acc, 0.f);
    }
    __syncthreads();

    // ---- fc3: [84] -> [10] + bias ----
    if (tid < IMG * 10) {
        int m = tid & 3;
        int n = tid >> 2;
        const float4* a = (const float4*)(lds + S_FC2 + m * 84);
        const float4* w = (const float4*)(fc3w + n * 84);
        float acc = fc3b[n];
        #pragma unroll
        for (int k = 0; k < 21; ++k) {
            float4 av = a[k], wv = w[k];
            acc = fmaf(av.x, wv.x, acc);
            acc = fmaf(av.y, wv.y, acc);
            acc = fmaf(av.z, wv.z, acc);
            acc = fmaf(av.w, wv.w, acc);
        }
        lds[S_LOG + m * 10 + n] = acc;
    }
    __syncthreads();

    // ---- softmax over 10 classes, one thread per image ----
    if (tid < IMG) {
        const float* lg = lds + S_LOG + tid * 10;
        float mx = lg[0];
        #pragma unroll
        for (int n = 1; n < 10; ++n) mx = fmaxf(mx, lg[n]);
        float e[10]; float sum = 0.f;
        #pragma unroll
        for (int n = 0; n < 10; ++n) { e[n] = expf(lg[n] - mx); sum += e[n]; }
        float inv = 1.f / sum;
        float* op = out + ((size_t)blk * IMG + tid) * 10;
        #pragma unroll
        for (int n = 0; n < 10; ++n) op[n] = e[n] * inv;
    }
}

extern "C" void kernel_launch(void* const* d_in, const int* in_sizes, int n_in,
                              void* d_out, int out_size, void* d_ws, size_t ws_size,
                              hipStream_t stream) {
    const float* x    = (const float*)d_in[0];
    const float* w1   = (const float*)d_in[1];
    const float* w2   = (const float*)d_in[2];
    const float* fw1  = (const float*)d_in[3];
    const float* fw2  = (const float*)d_in[4];
    const float* fc3w = (const float*)d_in[5];
    const float* fc3b = (const float*)d_in[6];
    float* outp = (float*)d_out;

    dim3 grid(16384 / IMG), block(THREADS);
    hipLaunchKernelGGL(lenet_kernel, grid, block, 0, stream,
                       x, w1, w2, fw1, fw2, fc3w, fc3b, outp);
}